// Round 10
// baseline (138.964 us; speedup 1.0000x reference)
//
#include <hip/hip_runtime.h>

#define NB 4
#define NC 64
#define NH 256
#define NW 256
#define TH 64                  // output rows per block (4 waves x 16 rows)

// 16B-aligned zeros: OOB rows load from here (branchless ptr select).
__device__ __attribute__((aligned(64))) float zbuf[16];

// ---------- phase 1: per-pixel g only (inv2 re-derived in phase 2, bitwise same) ----------
__global__ __launch_bounds__(256)
void wprep(const float* __restrict__ persp,
           const float* __restrict__ alpha_p,
           const float* __restrict__ beta_p,
           const float* __restrict__ gamma_p,
           float* __restrict__ wg)
{
    const float alpha = alpha_p[0];
    const float beta  = beta_p[0];
    const float gamma = gamma_p[0];
    const int i = (blockIdx.x * 256 + threadIdx.x) * 4;
    const float4 p = *(const float4*)(persp + i);
    const float pa[4] = {p.x, p.y, p.z, p.w};
    float g[4];
    #pragma unroll
    for (int k = 0; k < 4; ++k) {
        const float z  = fmaf(beta, pa[k], gamma);
        const float sg = __builtin_amdgcn_rcpf(1.0f + __expf(-z));
        const float sigma = fmaxf(alpha * sg, 1e-4f);
        const float t  = 0.5f * __builtin_amdgcn_rcpf(sigma * sigma);
        g[k] = __expf(-t);
    }
    *(float4*)(wg + i) = make_float4(g[0], g[1], g[2], g[3]);
}

// lane i <- lane i-1; lane 0 gets 0.0f (wave spans the image row -> zero-fill IS the pad)
__device__ __forceinline__ float dpp_shr1(float v) {
    return __int_as_float(__builtin_amdgcn_update_dpp(
        0, __float_as_int(v), 0x138 /*WAVE_SHR1*/, 0xf, 0xf, true));
}
// lane i <- lane i+1; lane 63 gets 0.0f (right pad)
__device__ __forceinline__ float dpp_shl1(float v) {
    return __int_as_float(__builtin_amdgcn_update_dpp(
        0, __float_as_int(v), 0x130 /*WAVE_SHL1*/, 0xf, 0xf, true));
}

// ---------- phase 2: PURE STREAMING — no LDS, no DMA, no barriers ----------
// 10th structural probe. Ledger: every LDS-based shape (monolithic r2-r7,
// dbuf r9) and every latency-source removal landed 43-46us at per-wave issue
// duty ~10-15%. This isolates the compute body: r0's streaming skeleton with
// r0's diseases cured (window 84->28 regs via DPP halos, transcendental
// chain -> wg table, rolling 1-ahead prefetches). If THIS is ~44us too, the
// wall is the body itself -> next round is packed-math/DPP surgery.
// (256,3): proven no-spill region. (256,4) spilled 3x — never again.
__global__ __launch_bounds__(256, 3)
void adaptive_gauss7(const float* __restrict__ x,
                     const float* __restrict__ wgp,
                     float* __restrict__ out)
{
    const int tid  = threadIdx.x;
    const int lane = tid & 63;
    const int wv   = tid >> 6;            // 4 waves x 16 rows = 64 rows
    const int c    = blockIdx.x;
    const int h0   = blockIdx.y * TH;
    const int b    = blockIdx.z;
    const int colbase = lane * 4;         // output cols colbase..colbase+3
    const int rg      = h0 + wv * 16;     // first output row of this wave

    const float* xc   = x   + (size_t)(b * NC + c) * NH * NW;
    float*       outp = out + (size_t)(b * NC + c) * NH * NW;
    const float* wrow = wgp + (size_t)b * NH * NW;

    // load one input row's own 4 columns (branchless OOB -> zeros)
    auto loadrow = [&](float dst[4], int gr) {
        const float* p = ((unsigned)gr < NH) ? (xc + (size_t)gr * NW + colbase) : zbuf;
        const float4 a = *(const float4*)p;
        dst[0] = a.x; dst[1] = a.y; dst[2] = a.z; dst[3] = a.w;
    };

    // window: 7 rows x 4 own cols. Input row gr lives in slot (gr-rg+3)%7.
    float win[7][4];
    #pragma unroll
    for (int r = 0; r < 7; ++r)
        loadrow(win[r], rg - 3 + r);

    float4 wcur = *(const float4*)(wrow + (size_t)rg * NW + colbase);

    #pragma unroll
    for (int o = 0; o < 16; ++o) {
        // (a) prefetch input row rg+o+4 (bottom tap of NEXT iteration) —
        //     issued before the compute so HBM/L2 latency hides under it
        float nxt[4];
        if (o < 15)
            loadrow(nxt, rg + o + 4);
        // (b) prefetch next row's g
        float4 wnxt;
        if (o < 15)
            wnxt = *(const float4*)(wrow + (size_t)(rg + o + 1) * NW + colbase);

        // (c) per-pixel weight powers (inv2 via wprep's exact op sequence)
        const float gk[4] = {wcur.x, wcur.y, wcur.z, wcur.w};
        float g[4], p4[4], p9[4], inv2[4];
        #pragma unroll
        for (int k = 0; k < 4; ++k) {
            g[k] = gk[k];
            const float g2 = g[k] * g[k];
            p4[k] = g2 * g2;
            p9[k] = p4[k] * p4[k] * g[k];
            const float S  = fmaf(2.0f, (g[k] + p4[k]) + p9[k], 1.0f);
            const float iv = __builtin_amdgcn_rcpf(S);
            inv2[k] = iv * iv;
        }

        // (d) horizontal: 1 stored row + 6 DPP halos -> 10-wide window, per 7 rows
        float s0[4], s1[4], s2[4], s3[4];
        #pragma unroll
        for (int j = 0; j < 7; ++j) {
            const int s = (o + j) % 7;      // static after unroll
            const float w[10] = {
                dpp_shr1(win[s][1]),        // col -3
                dpp_shr1(win[s][2]),        // col -2
                dpp_shr1(win[s][3]),        // col -1
                win[s][0], win[s][1], win[s][2], win[s][3],
                dpp_shl1(win[s][0]),        // col +4
                dpp_shl1(win[s][1]),        // col +5
                dpp_shl1(win[s][2])         // col +6
            };
            #pragma unroll
            for (int k = 0; k < 4; ++k) {
                const float rs = fmaf(p9[k], w[k]     + w[k + 6],
                                 fmaf(p4[k], w[k + 1] + w[k + 5],
                                 fmaf(g[k],  w[k + 2] + w[k + 4],
                                             w[k + 3])));
                if      (j == 0) s0[k] = rs;
                else if (j == 1) s1[k] = rs;
                else if (j == 2) s2[k] = rs;
                else if (j == 3) s3[k] = rs;
                else if (j == 4) s2[k] = s2[k] + rs;
                else if (j == 5) s1[k] = s1[k] + rs;
                else             s0[k] = s0[k] + rs;
            }
        }

        // (e) vertical combine — same association as rounds 0-9 (bitwise same)
        float res[4];
        #pragma unroll
        for (int k = 0; k < 4; ++k) {
            res[k] = fmaf(p9[k], s0[k],
                     fmaf(p4[k], s1[k],
                     fmaf(g[k],  s2[k], s3[k]))) * inv2[k];
        }
        *(float4*)(outp + (size_t)(rg + o) * NW + colbase) =
            make_float4(res[0], res[1], res[2], res[3]);

        // (f) commit prefetched row into the now-dead slot
        if (o < 15) {
            win[o % 7][0] = nxt[0]; win[o % 7][1] = nxt[1];
            win[o % 7][2] = nxt[2]; win[o % 7][3] = nxt[3];
            wcur = wnxt;
        }
    }
}

extern "C" void kernel_launch(void* const* d_in, const int* in_sizes, int n_in,
                              void* d_out, int out_size, void* d_ws, size_t ws_size,
                              hipStream_t stream) {
    const float* x     = (const float*)d_in[0];
    const float* persp = (const float*)d_in[1];
    const float* alpha = (const float*)d_in[2];
    const float* beta  = (const float*)d_in[3];
    const float* gamma = (const float*)d_in[4];
    float* outp        = (float*)d_out;
    float* wg          = (float*)d_ws;       // 4*256*256 floats = 1 MiB

    wprep<<<dim3((NB * NH * NW) / 1024), dim3(256), 0, stream>>>(persp, alpha, beta, gamma, wg);
    // 64 x 4 x 4 = 1024 blocks; no LDS -> residency reg-limited (~3 blocks/CU)
    adaptive_gauss7<<<dim3(NC, NH / TH, NB), dim3(256), 0, stream>>>(x, wg, outp);
}